// Round 1
// baseline (225.653 us; speedup 1.0000x reference)
//
#include <hip/hip_runtime.h>
#include <hip/hip_bf16.h>
#include <stdint.h>

// Problem constants
#define DIMC 512
#define NHEADS 8
#define HDIM 64
#define BATCH 8
#define NTOK 1024            // 32*32
#define MTOT (BATCH*NTOK)    // 8192

typedef __attribute__((ext_vector_type(8))) __bf16 bf16x8;
typedef __attribute__((ext_vector_type(4))) float f32x4;
typedef unsigned short u16;

typedef const __attribute__((address_space(1))) uint8_t glob_u8;
typedef __attribute__((address_space(3))) uint8_t lds_u8;

#define LOG2E 1.44269504088896f
#define ATTN_SCALE 0.125f

__device__ __forceinline__ void gload16(const void* src, void* dst) {
  __builtin_amdgcn_global_load_lds((glob_u8*)src, (lds_u8*)dst, 16, 0, 0);
}

// ---------------------------------------------------------------------------
// Generic batched f32 -> bf16 transpose:  in [bz][R][C] -> out [bz][C][R]
// out row stride = ldo (elements), batch strides in elements.
// ---------------------------------------------------------------------------
__global__ void transpose_f32_bf16(const float* __restrict__ in,
                                   u16* __restrict__ out,
                                   int R, int C, long ibs, long obs, int ldo) {
  __shared__ float t[32][33];
  int bz = blockIdx.z;
  in  += (long)bz * ibs;
  out += (long)bz * obs;
  int r0 = blockIdx.y * 32, c0 = blockIdx.x * 32;
  int tx = threadIdx.x, ty = threadIdx.y;   // block (32, 8)
  #pragma unroll
  for (int i = 0; i < 4; ++i) {
    int r = r0 + ty + i * 8;
    t[ty + i * 8][tx] = in[(long)r * C + c0 + tx];
  }
  __syncthreads();
  #pragma unroll
  for (int i = 0; i < 4; ++i) {
    int c = c0 + ty + i * 8;
    __hip_bfloat16 h = __float2bfloat16(t[tx][ty + i * 8]);
    out[(long)c * ldo + r0 + tx] = *(u16*)&h;
  }
}

// ---------------------------------------------------------------------------
// 128x128x(K=512) bf16 MFMA GEMM, m97-style: global_load_lds w16 staging with
// XOR-swizzled LDS ( byte ^= (row&7)<<4 ) to avoid 16-way ds_read_b128 bank
// conflicts. 4 waves, each computes a 64x64 quadrant as 4x4 16x16x32 frags.
//
// MODE 0: A = x [8192][512], Bt = Wqk_t [1024][512]
//         out: q_buf/k_buf bf16 [b,h,n,d] (+bias0=bq, bias1=bk)
// MODE 1: A = Wv_t [512][512], Bt = x [8192][512]
//         out: vt_buf bf16 [b,h,d,n] (+bias0=bv)
// MODE 2: A = Wo_t [512][512], Bt = head_out [8192][512]
//         out: f32 [b][512][1024] (+bias0=bo)
// ---------------------------------------------------------------------------
template<int MODE>
__global__ __launch_bounds__(256) void gemm_k(
    const u16* __restrict__ A, const u16* __restrict__ Bt,
    const float* __restrict__ bias0, const float* __restrict__ bias1,
    u16* __restrict__ o0, u16* __restrict__ o1, float* __restrict__ of) {
  constexpr int K = 512;
  __shared__ __align__(16) char As[128 * 64 * 2];
  __shared__ __align__(16) char Bs[128 * 64 * 2];
  int tid = threadIdx.x, wave = tid >> 6, lane = tid & 63;
  int lo = lane & 15, hi = lane >> 4;
  int row0 = blockIdx.x * 128, col0 = blockIdx.y * 128;
  int wr = wave >> 1, wc = wave & 1;

  f32x4 acc[4][4] = {};

  const char* Ab = (const char*)A;
  const char* Bb = (const char*)Bt;

  for (int ks = 0; ks < 8; ++ks) {
    int k0 = ks * 64;
    #pragma unroll
    for (int i = 0; i < 4; ++i) {
      int ch = wave * 4 + i;
      int o = ch * 1024 + lane * 16;
      int r = o >> 7;                          // row within 128-row tile
      int w = (o & 127) ^ ((r & 7) << 4);      // swizzled within-row byte
      gload16(Ab + ((long)(row0 + r) * K + k0) * 2 + w, As + ch * 1024);
      gload16(Bb + ((long)(col0 + r) * K + k0) * 2 + w, Bs + ch * 1024);
    }
    __syncthreads();
    #pragma unroll
    for (int kk = 0; kk < 2; ++kk) {
      int kb = kk * 64 + hi * 16;
      bf16x8 af[4], bfr[4];
      #pragma unroll
      for (int m = 0; m < 4; ++m) {
        int r = wr * 64 + m * 16 + lo;
        af[m] = *(const bf16x8*)(As + ((r * 128 + kb) ^ ((r & 7) << 4)));
      }
      #pragma unroll
      for (int n = 0; n < 4; ++n) {
        int r = wc * 64 + n * 16 + lo;
        bfr[n] = *(const bf16x8*)(Bs + ((r * 128 + kb) ^ ((r & 7) << 4)));
      }
      #pragma unroll
      for (int m = 0; m < 4; ++m)
        #pragma unroll
        for (int n = 0; n < 4; ++n)
          acc[m][n] = __builtin_amdgcn_mfma_f32_16x16x32_bf16(af[m], bfr[n], acc[m][n], 0, 0, 0);
    }
    __syncthreads();
  }

  // epilogue: C/D layout  row = hi*4+r, col = lo  within each 16x16 frag
  #pragma unroll
  for (int m = 0; m < 4; ++m)
    #pragma unroll
    for (int n = 0; n < 4; ++n)
      #pragma unroll
      for (int r = 0; r < 4; ++r) {
        float v = acc[m][n][r];
        int rr = row0 + wr * 64 + m * 16 + hi * 4 + r;
        int cc = col0 + wc * 64 + n * 16 + lo;
        if constexpr (MODE == 0) {
          int b = rr >> 10, nn = rr & 1023;
          if (cc < 512) {
            float val = v + bias0[cc];
            int h = cc >> 6, d = cc & 63;
            __hip_bfloat16 hb = __float2bfloat16(val);
            o0[((b * 8 + h) << 16) + (nn << 6) + d] = *(u16*)&hb;
          } else {
            int j = cc - 512;
            float val = v + bias1[j];
            int h = j >> 6, d = j & 63;
            __hip_bfloat16 hb = __float2bfloat16(val);
            o1[((b * 8 + h) << 16) + (nn << 6) + d] = *(u16*)&hb;
          }
        } else if constexpr (MODE == 1) {
          int b = cc >> 10, nn = cc & 1023;
          float val = v + bias0[rr];
          __hip_bfloat16 hb = __float2bfloat16(val);
          o0[b * 524288 + rr * 1024 + nn] = *(u16*)&hb;
        } else {
          int b = cc >> 10, nn = cc & 1023;
          of[b * 524288 + rr * 1024 + nn] = v + bias0[rr];
        }
      }
}

// ---------------------------------------------------------------------------
// Flash attention: grid (8, 64) = (q-chunk of 128, b*h). Block = 4 waves,
// each wave owns 32 q-rows. K tile [64 keys][64 d] and V^T tile [64 d][64 keys]
// staged via swizzled global_load_lds. Online softmax in C-frag layout with
// 16-lane shfl_xor row reduces; P goes through padded per-wave LDS to become
// an A-fragment for PV.
// ---------------------------------------------------------------------------
__global__ __launch_bounds__(256) void attn_k(
    const u16* __restrict__ qb, const u16* __restrict__ kb,
    const u16* __restrict__ vtb, u16* __restrict__ ho) {
  __shared__ __align__(16) char Ks[8192];
  __shared__ __align__(16) char Vs[8192];
  __shared__ __align__(16) char Ps[4][32 * 144];

  int bh = blockIdx.y;
  int tid = threadIdx.x, wave = tid >> 6, lane = tid & 63;
  int lo = lane & 15, hi = lane >> 4;
  int qw = blockIdx.x * 128 + wave * 32;

  // Q fragments in registers: 32 rows x 64 d
  bf16x8 aq[2][2];
  const char* qbase = (const char*)qb + ((bh * NTOK + qw) * HDIM) * 2;
  #pragma unroll
  for (int m = 0; m < 2; ++m)
    #pragma unroll
    for (int kk = 0; kk < 2; ++kk)
      aq[m][kk] = *(const bf16x8*)(qbase + (m * 16 + lo) * 128 + kk * 64 + hi * 16);

  f32x4 accO[2][4] = {};
  float mrow[2][4], lrow[2][4];
  #pragma unroll
  for (int m = 0; m < 2; ++m)
    #pragma unroll
    for (int r = 0; r < 4; ++r) { mrow[m][r] = -__builtin_inff(); lrow[m][r] = 0.f; }

  const char* kbase = (const char*)kb + (long)bh * NTOK * HDIM * 2;
  const char* vtbase = (const char*)vtb + (long)bh * HDIM * NTOK * 2;
  char* Pw = Ps[wave];

  for (int kt = 0; kt < 16; ++kt) {
    #pragma unroll
    for (int i = 0; i < 2; ++i) {
      int ch = wave * 2 + i;
      int o = ch * 1024 + lane * 16;
      int r = o >> 7;
      int w = (o & 127) ^ ((r & 7) << 4);
      gload16(kbase + kt * 8192 + r * 128 + w, Ks + ch * 1024);
      gload16(vtbase + (long)r * 2048 + kt * 128 + w, Vs + ch * 1024);
    }
    __syncthreads();

    // S = Q @ K^T  (rows q, cols keys)
    f32x4 s[2][4] = {};
    #pragma unroll
    for (int kk = 0; kk < 2; ++kk) {
      int kbyte = kk * 64 + hi * 16;
      bf16x8 bk_[4];
      #pragma unroll
      for (int n = 0; n < 4; ++n) {
        int r = n * 16 + lo;
        bk_[n] = *(const bf16x8*)(Ks + ((r * 128 + kbyte) ^ ((r & 7) << 4)));
      }
      #pragma unroll
      for (int m = 0; m < 2; ++m)
        #pragma unroll
        for (int n = 0; n < 4; ++n)
          s[m][n] = __builtin_amdgcn_mfma_f32_16x16x32_bf16(aq[m][kk], bk_[n], s[m][n], 0, 0, 0);
    }

    // online softmax (per-row over 4 n-frags x 16 col-lanes)
    #pragma unroll
    for (int m = 0; m < 2; ++m)
      #pragma unroll
      for (int r = 0; r < 4; ++r) {
        float mx = fmaxf(fmaxf(s[m][0][r], s[m][1][r]), fmaxf(s[m][2][r], s[m][3][r]));
        mx = fmaxf(mx, __shfl_xor(mx, 1));
        mx = fmaxf(mx, __shfl_xor(mx, 2));
        mx = fmaxf(mx, __shfl_xor(mx, 4));
        mx = fmaxf(mx, __shfl_xor(mx, 8));
        float mnew = fmaxf(mrow[m][r], mx * ATTN_SCALE);
        float corr = exp2f((mrow[m][r] - mnew) * LOG2E);
        mrow[m][r] = mnew;
        float bexp = mnew * LOG2E;
        float rsum = 0.f;
        #pragma unroll
        for (int n = 0; n < 4; ++n) {
          float p = exp2f(s[m][n][r] * (ATTN_SCALE * LOG2E) - bexp);
          s[m][n][r] = p;
          rsum += p;
        }
        rsum += __shfl_xor(rsum, 1);
        rsum += __shfl_xor(rsum, 2);
        rsum += __shfl_xor(rsum, 4);
        rsum += __shfl_xor(rsum, 8);
        lrow[m][r] = lrow[m][r] * corr + rsum;
        #pragma unroll
        for (int n = 0; n < 4; ++n) accO[m][n][r] *= corr;
      }

    // P -> per-wave LDS (padded stride 144B), then re-read as A-frags
    #pragma unroll
    for (int m = 0; m < 2; ++m)
      #pragma unroll
      for (int n = 0; n < 4; ++n)
        #pragma unroll
        for (int r = 0; r < 4; ++r) {
          __hip_bfloat16 hb = __float2bfloat16(s[m][n][r]);
          *(u16*)(Pw + (m * 16 + hi * 4 + r) * 144 + (n * 16 + lo) * 2) = *(u16*)&hb;
        }

    // O += P @ V
    #pragma unroll
    for (int kk = 0; kk < 2; ++kk) {
      int kbyte = kk * 64 + hi * 16;
      bf16x8 pa[2], vb[4];
      #pragma unroll
      for (int m = 0; m < 2; ++m)
        pa[m] = *(const bf16x8*)(Pw + (m * 16 + lo) * 144 + kk * 64 + hi * 16);
      #pragma unroll
      for (int n = 0; n < 4; ++n) {
        int r = n * 16 + lo;
        vb[n] = *(const bf16x8*)(Vs + ((r * 128 + kbyte) ^ ((r & 7) << 4)));
      }
      #pragma unroll
      for (int m = 0; m < 2; ++m)
        #pragma unroll
        for (int n = 0; n < 4; ++n)
          accO[m][n] = __builtin_amdgcn_mfma_f32_16x16x32_bf16(pa[m], vb[n], accO[m][n], 0, 0, 0);
    }
    __syncthreads();
  }

  // epilogue: head_out [b,n][h*64+d] bf16
  int b = bh >> 3, h = bh & 7;
  #pragma unroll
  for (int m = 0; m < 2; ++m)
    #pragma unroll
    for (int r = 0; r < 4; ++r) {
      float inv = 1.f / lrow[m][r];
      int tok = qw + m * 16 + hi * 4 + r;
      #pragma unroll
      for (int n = 0; n < 4; ++n) {
        float val = accO[m][n][r] * inv;
        __hip_bfloat16 hb = __float2bfloat16(val);
        ho[((b * NTOK + tok) << 9) + h * 64 + n * 16 + lo] = *(u16*)&hb;
      }
    }
}

// ---------------------------------------------------------------------------
// Launch
// ---------------------------------------------------------------------------
extern "C" void kernel_launch(void* const* d_in, const int* in_sizes, int n_in,
                              void* d_out, int out_size, void* d_ws, size_t ws_size,
                              hipStream_t stream) {
  const float* query = (const float*)d_in[0];
  const float* Wq = (const float*)d_in[1];
  const float* bq = (const float*)d_in[2];
  const float* Wk = (const float*)d_in[3];
  const float* bk = (const float*)d_in[4];
  const float* Wv = (const float*)d_in[5];
  const float* bv = (const float*)d_in[6];
  const float* Wo = (const float*)d_in[7];
  const float* bo = (const float*)d_in[8];

  char* ws = (char*)d_ws;
  // workspace layout (bytes)
  u16* x_bf   = (u16*)(ws + 0);          // [8192][512]        8 MB
  u16* Wqk_t  = (u16*)(ws + 8388608);    // [1024][512]        1 MB
  u16* Wv_t   = (u16*)(ws + 9437184);    // [512][512]         0.5 MB
  u16* Wo_t   = (u16*)(ws + 9961472);    // [512][512]         0.5 MB
  u16* q_buf  = (u16*)(ws + 10485760);   // [64][1024][64]     8 MB
  u16* k_buf  = (u16*)(ws + 18874368);   // [64][1024][64]     8 MB
  u16* vt_buf = (u16*)(ws + 27262976);   // [64][64][1024]     8 MB
  u16* ho_buf = (u16*)(ws + 35651584);   // [8192][512]        8 MB

  dim3 tb(32, 8, 1);
  // x = transpose(query): per b, [512][1024] -> [1024][512]
  transpose_f32_bf16<<<dim3(32, 16, 8), tb, 0, stream>>>(
      query, x_bf, 512, 1024, 512L * 1024, 1024L * 512, 512);
  // Wq[h]: [512][64] -> rows h*64+d of Wqk_t
  transpose_f32_bf16<<<dim3(2, 16, 8), tb, 0, stream>>>(
      Wq, Wqk_t, 512, 64, 32768L, 32768L, 512);
  transpose_f32_bf16<<<dim3(2, 16, 8), tb, 0, stream>>>(
      Wk, Wqk_t + 512 * 512, 512, 64, 32768L, 32768L, 512);
  transpose_f32_bf16<<<dim3(2, 16, 8), tb, 0, stream>>>(
      Wv, Wv_t, 512, 64, 32768L, 32768L, 512);
  transpose_f32_bf16<<<dim3(16, 16, 1), tb, 0, stream>>>(
      Wo, Wo_t, 512, 512, 0L, 0L, 512);

  // QKV projections
  gemm_k<0><<<dim3(64, 8), 256, 0, stream>>>(x_bf, Wqk_t, bq, bk, q_buf, k_buf, nullptr);
  gemm_k<1><<<dim3(4, 64), 256, 0, stream>>>(Wv_t, x_bf, bv, nullptr, vt_buf, nullptr, nullptr);

  // attention
  attn_k<<<dim3(8, 64), 256, 0, stream>>>(q_buf, k_buf, vt_buf, ho_buf);

  // output projection (writes f32 [b][512][1024] = output layout)
  gemm_k<2><<<dim3(4, 64), 256, 0, stream>>>(Wo_t, ho_buf, bo, nullptr, nullptr, nullptr, (float*)d_out);
}

// Round 6
// 163.210 us; speedup vs baseline: 1.3826x; 1.3826x over previous
//
#include <hip/hip_runtime.h>
#include <hip/hip_bf16.h>
#include <stdint.h>

// Problem constants
#define DIMC 512
#define NHEADS 8
#define HDIM 64
#define BATCH 8
#define NTOK 1024            // 32*32
#define MTOT (BATCH*NTOK)    // 8192

typedef __attribute__((ext_vector_type(8))) __bf16 bf16x8;
typedef __attribute__((ext_vector_type(4))) float f32x4;
typedef __attribute__((ext_vector_type(16))) float f32x16;
typedef __attribute__((ext_vector_type(4))) unsigned uint4v;
typedef unsigned short u16;

typedef const __attribute__((address_space(1))) uint8_t glob_u8;
typedef __attribute__((address_space(3))) uint8_t lds_u8;

#define LOG2E 1.44269504088896f
#define ATTN_SCALE 0.125f

__device__ __forceinline__ void gload16(const void* src, void* dst) {
  __builtin_amdgcn_global_load_lds((glob_u8*)src, (lds_u8*)dst, 16, 0, 0);
}

__device__ __forceinline__ u16 bf16bits(float v) {
  __hip_bfloat16 h = __float2bfloat16(v);
  return *(u16*)&h;
}

// v_cvt_pk_bf16_f32: pack two f32 -> two bf16 in one u32 (lo=first arg)
__device__ __forceinline__ unsigned cvtpk(float lo, float hi) {
  unsigned r;
  asm("v_cvt_pk_bf16_f32 %0, %1, %2" : "=v"(r) : "v"(lo), "v"(hi));
  return r;
}

// permlane32_swap pair: a' = [a.lo | b.lo(from lanes 0-31)], b' = [a.hi | b.hi]
__device__ __forceinline__ void plswap(unsigned &a, unsigned &b) {
  auto r = __builtin_amdgcn_permlane32_swap(a, b, false, false);
  a = r[0]; b = r[1];
}

__device__ __forceinline__ float xhalf_max(float x) {
  unsigned u = __builtin_bit_cast(unsigned, x);
  auto r = __builtin_amdgcn_permlane32_swap(u, u, false, false);
  return fmaxf(__builtin_bit_cast(float, r[0]), __builtin_bit_cast(float, r[1]));
}

__device__ __forceinline__ float xhalf_add(float x) {
  unsigned u = __builtin_bit_cast(unsigned, x);
  auto r = __builtin_amdgcn_permlane32_swap(u, u, false, false);
  return __builtin_bit_cast(float, r[0]) + __builtin_bit_cast(float, r[1]);
}

__device__ __forceinline__ bf16x8 mk8(unsigned a, unsigned b, unsigned c, unsigned d) {
  uint4v u; u.x = a; u.y = b; u.z = c; u.w = d;
  return __builtin_bit_cast(bf16x8, u);
}

// ---------------------------------------------------------------------------
// Transposes: f32 [R][C] -> bf16 [C][R-ish] tiles
// ---------------------------------------------------------------------------
__global__ void transpose_f32_bf16(const float* __restrict__ in,
                                   u16* __restrict__ out,
                                   int R, int C, long ibs, long obs, int ldo) {
  __shared__ float t[32][33];
  int bz = blockIdx.z;
  in  += (long)bz * ibs;
  out += (long)bz * obs;
  int r0 = blockIdx.y * 32, c0 = blockIdx.x * 32;
  int tx = threadIdx.x, ty = threadIdx.y;   // block (32, 8)
  #pragma unroll
  for (int i = 0; i < 4; ++i) {
    int r = r0 + ty + i * 8;
    t[ty + i * 8][tx] = in[(long)r * C + c0 + tx];
  }
  __syncthreads();
  #pragma unroll
  for (int i = 0; i < 4; ++i) {
    int c = c0 + ty + i * 8;
    out[(long)c * ldo + r0 + tx] = bf16bits(t[tx][ty + i * 8]);
  }
}

// Fused Wq/Wk/Wv transpose: grid (2, 16, 24); z = w*8+head
__global__ void wqkv_trans(const float* __restrict__ Wq, const float* __restrict__ Wk,
                           const float* __restrict__ Wv,
                           u16* __restrict__ Wqk_t, u16* __restrict__ Wv_t) {
  __shared__ float t[32][33];
  int z = blockIdx.z; int w = z >> 3, head = z & 7;
  const float* in = (w == 0 ? Wq : (w == 1 ? Wk : Wv)) + head * 32768;
  u16* out = (w == 0 ? Wqk_t : (w == 1 ? Wqk_t + 262144 : Wv_t)) + head * 32768;
  int r0 = blockIdx.y * 32, c0 = blockIdx.x * 32;
  int tx = threadIdx.x, ty = threadIdx.y;
  #pragma unroll
  for (int i = 0; i < 4; ++i) {
    int r = r0 + ty + i * 8;
    t[ty + i * 8][tx] = in[(long)r * 64 + c0 + tx];
  }
  __syncthreads();
  #pragma unroll
  for (int i = 0; i < 4; ++i) {
    int c = c0 + ty + i * 8;
    out[(long)c * 512 + r0 + tx] = bf16bits(t[tx][ty + i * 8]);
  }
}

// ---------------------------------------------------------------------------
// 128x128x(K=512) bf16 MFMA GEMM (m97-style, swizzled global_load_lds w16).
// MODE 0: A = x [8192][512], Bt = Wqk_t [1024][512]
//         -> Q/K scattered into MFMA-frag-ready layouts
//            q_buf/k_buf: [bh][t32][ks4][lane64][j8] bf16
//            (elem = X[bh][t*32 + (l&31)][16ks + 8(l>>5) + j])
// MODE 1: A = Wv_t [512][512], Bt = x [8192][512]
//         -> v_buf: [bh][kv32][ks2][n2][lane64][j8] bf16
//            (elem = V[bh][kv*32 + 16ks + 8(l>>5)+j][32n + (l&31)])
// MODE 2: A = Wo_t [512][512], Bt = head_out [8192][512] -> f32 output
// ---------------------------------------------------------------------------
template<int MODE>
__global__ __launch_bounds__(256) void gemm_k(
    const u16* __restrict__ A, const u16* __restrict__ Bt,
    const float* __restrict__ bias0, const float* __restrict__ bias1,
    u16* __restrict__ o0, u16* __restrict__ o1, float* __restrict__ of) {
  constexpr int K = 512;
  __shared__ __align__(16) char As[128 * 64 * 2];
  __shared__ __align__(16) char Bs[128 * 64 * 2];
  int tid = threadIdx.x, wave = tid >> 6, lane = tid & 63;
  int lo = lane & 15, hi = lane >> 4;
  int row0 = blockIdx.x * 128, col0 = blockIdx.y * 128;
  int wr = wave >> 1, wc = wave & 1;

  f32x4 acc[4][4] = {};

  const char* Ab = (const char*)A;
  const char* Bb = (const char*)Bt;

  for (int ks = 0; ks < 8; ++ks) {
    int k0 = ks * 64;
    #pragma unroll
    for (int i = 0; i < 4; ++i) {
      int ch = wave * 4 + i;
      int o = ch * 1024 + lane * 16;
      int r = o >> 7;                          // row within 128-row tile
      int w = (o & 127) ^ ((r & 7) << 4);      // swizzled within-row byte
      gload16(Ab + ((long)(row0 + r) * K + k0) * 2 + w, As + ch * 1024);
      gload16(Bb + ((long)(col0 + r) * K + k0) * 2 + w, Bs + ch * 1024);
    }
    __syncthreads();
    #pragma unroll
    for (int kk = 0; kk < 2; ++kk) {
      int kb = kk * 64 + hi * 16;
      bf16x8 af[4], bfr[4];
      #pragma unroll
      for (int m = 0; m < 4; ++m) {
        int r = wr * 64 + m * 16 + lo;
        af[m] = *(const bf16x8*)(As + ((r * 128 + kb) ^ ((r & 7) << 4)));
      }
      #pragma unroll
      for (int n = 0; n < 4; ++n) {
        int r = wc * 64 + n * 16 + lo;
        bfr[n] = *(const bf16x8*)(Bs + ((r * 128 + kb) ^ ((r & 7) << 4)));
      }
      #pragma unroll
      for (int m = 0; m < 4; ++m)
        #pragma unroll
        for (int n = 0; n < 4; ++n)
          acc[m][n] = __builtin_amdgcn_mfma_f32_16x16x32_bf16(af[m], bfr[n], acc[m][n], 0, 0, 0);
    }
    __syncthreads();
  }

  // epilogue: C/D frag layout  row = hi*4+r, col = lo
  #pragma unroll
  for (int m = 0; m < 4; ++m)
    #pragma unroll
    for (int n = 0; n < 4; ++n)
      #pragma unroll
      for (int r = 0; r < 4; ++r) {
        float v = acc[m][n][r];
        int rr = row0 + wr * 64 + m * 16 + hi * 4 + r;
        int cc = col0 + wc * 64 + n * 16 + lo;
        if constexpr (MODE == 0) {
          int b = rr >> 10, nn = rr & 1023;
          int isK = cc >> 9;
          int c2 = cc & 511;
          int head = c2 >> 6, d = c2 & 63;
          float val = v + (isK ? bias1[c2] : bias0[c2]);
          int bh2 = b * 8 + head;
          int t = nn >> 5, l31q = nn & 31;
          int kss = d >> 4, hh = (d >> 3) & 1, j = d & 7;
          long off = (((long)(bh2 * 32 + t) * 4 + kss) * 64 + (l31q + 32 * hh)) * 8 + j;
          (isK ? o1 : o0)[off] = bf16bits(val);
        } else if constexpr (MODE == 1) {
          int b = cc >> 10, nn = cc & 1023;
          int head = rr >> 6, d = rr & 63;
          float val = v + bias0[rr];
          int bh2 = b * 8 + head;
          int kv = nn >> 5, ki = nn & 31;
          int kss = ki >> 4, hh = (ki >> 3) & 1, j = ki & 7;
          int n2 = d >> 5, l31v = d & 31;
          long off = ((((long)(bh2 * 32 + kv) * 2 + kss) * 2 + n2) * 64 + (l31v + 32 * hh)) * 8 + j;
          o0[off] = bf16bits(val);
        } else {
          int b = cc >> 10, nn = cc & 1023;
          of[b * 524288 + rr * 1024 + nn] = v + bias0[rr];
        }
      }
}

// ---------------------------------------------------------------------------
// Flash attention, m214-style swapped-QK^T 32x32x16 structure.
// Grid: 512 blocks x 256 thr (4 independent waves; wave = 32 q-rows).
// No LDS tiles, no barriers. All operands read as frag-ready coalesced
// global loads (L2-resident). Softmax fully in-lane; P stays in registers
// via cvt_pk_bf16 + permlane32_swap; defer-max rescale (THR=8).
// ---------------------------------------------------------------------------
struct Frags { bf16x8 k[4]; bf16x8 v[2][2]; };

__device__ __forceinline__ void load_frags(Frags& f, const char* kb, const char* vb,
                                           int kv, int lane16) {
  const char* kp = kb + kv * 4096 + lane16;
  f.k[0] = *(const bf16x8*)(kp);
  f.k[1] = *(const bf16x8*)(kp + 1024);
  f.k[2] = *(const bf16x8*)(kp + 2048);
  f.k[3] = *(const bf16x8*)(kp + 3072);
  const char* vp = vb + kv * 4096 + lane16;
  f.v[0][0] = *(const bf16x8*)(vp);
  f.v[0][1] = *(const bf16x8*)(vp + 1024);
  f.v[1][0] = *(const bf16x8*)(vp + 2048);
  f.v[1][1] = *(const bf16x8*)(vp + 3072);
}

__global__ __launch_bounds__(256) void attn_k(
    const u16* __restrict__ qf, const u16* __restrict__ kf,
    const u16* __restrict__ vf, u16* __restrict__ ho) {
  __shared__ float redf[4][32];
  int tid = threadIdx.x, wave = tid >> 6, lane = tid & 63;
  int l31 = lane & 31, h = lane >> 5;
  // XCD-friendly decode: all 8 q-chunks of a bh on one XCD
  int id = blockIdx.x;                 // [0,512)
  int xcd = id & 7, rest = id >> 3;    // rest in [0,64)
  int bh = xcd * 8 + (rest >> 3);
  int qt = (rest & 7) * 4 + wave;      // 32-row q-tile [0,32)

  int lane16 = lane * 16;
  const char* qb = (const char*)qf + (long)(bh * 32 + qt) * 4096;
  const char* kb = (const char*)kf + (long)bh * 131072;
  const char* vb = (const char*)vf + (long)bh * 131072;

  bf16x8 qfrag[4];
  #pragma unroll
  for (int ks = 0; ks < 4; ++ks)
    qfrag[ks] = *(const bf16x8*)(qb + ks * 1024 + lane16);

  f32x16 accO0 = {}, accO1 = {};
  float mreg = -__builtin_inff(), lsum = 0.f;
  const float C1 = ATTN_SCALE * LOG2E;

  auto step = [&](const Frags& f) {
    f32x16 s = {};
    #pragma unroll
    for (int ks = 0; ks < 4; ++ks)
      s = __builtin_amdgcn_mfma_f32_32x32x16_bf16(f.k[ks], qfrag[ks], s, 0, 0, 0);
    // in-lane row max over 16 regs + cross-half swap
    float mx = fmaxf(s[0], s[1]);
    #pragma unroll
    for (int r = 2; r < 16; ++r) mx = fmaxf(mx, s[r]);
    mx = xhalf_max(mx);
    float scaled = mx * ATTN_SCALE;
    if (__any(scaled > mreg + 8.f)) {
      float mnew = fmaxf(mreg, scaled);
      float corr = exp2f((mreg - mnew) * LOG2E);
      redf[wave][l31] = corr;
      asm volatile("s_waitcnt lgkmcnt(0)" ::: "memory");
      #pragma unroll
      for (int r = 0; r < 16; ++r) {
        float cf = redf[wave][(r & 3) + 8 * (r >> 2) + 4 * h];
        accO0[r] *= cf; accO1[r] *= cf;
      }
      lsum *= corr;
      mreg = mnew;
    }
    float mb = mreg * LOG2E;
    float p[16]; float rs = 0.f;
    #pragma unroll
    for (int r = 0; r < 16; ++r) { p[r] = exp2f(fmaf(s[r], C1, -mb)); rs += p[r]; }
    lsum += xhalf_add(rs);
    // P (f32, P^T layout) -> bf16 A-frags via cvt_pk + permlane32_swap
    unsigned w0 = cvtpk(p[0], p[1]),  w1 = cvtpk(p[2], p[3]);
    unsigned w2 = cvtpk(p[4], p[5]),  w3 = cvtpk(p[6], p[7]);
    unsigned w4 = cvtpk(p[8], p[9]),  w5 = cvtpk(p[10], p[11]);
    unsigned w6 = cvtpk(p[12], p[13]), w7 = cvtpk(p[14], p[15]);
    plswap(w0, w2); plswap(w1, w3); plswap(w4, w6); plswap(w5, w7);
    bf16x8 pa0 = mk8(w0, w1, w2, w3);
    bf16x8 pa1 = mk8(w4, w5, w6, w7);
    accO0 = __builtin_amdgcn_mfma_f32_32x32x16_bf16(pa0, f.v[0][0], accO0, 0, 0, 0);
    accO0 = __builtin_amdgcn_mfma_f32_32x32x16_bf16(pa1, f.v[1][0], accO0, 0, 0, 0);
    accO1 = __builtin_amdgcn_mfma_f32_32x32x16_bf16(pa0, f.v[0][1], accO1, 0, 0, 0);
    accO1 = __builtin_amdgcn_mfma_f32_32x32x16_bf16(pa1, f.v[1][1], accO1, 0, 0, 0);
  };

  Frags fA, fB;
  load_frags(fA, kb, vb, 0, lane16);
  for (int i = 0; i < 16; ++i) {
    load_frags(fB, kb, vb, 2 * i + 1, lane16);
    step(fA);
    if (i < 15) load_frags(fA, kb, vb, 2 * i + 2, lane16);
    step(fB);
  }

  // epilogue: redistribute 1/lsum across the C-layout rows, write head_out
  float linv = 1.f / lsum;
  redf[wave][l31] = linv;
  asm volatile("s_waitcnt lgkmcnt(0)" ::: "memory");
  int b = bh >> 3, head = bh & 7;
  u16* hob = ho + ((long)b * 1024 + qt * 32) * 512 + head * 64;
  #pragma unroll
  for (int r = 0; r < 16; ++r) {
    int row = (r & 3) + 8 * (r >> 2) + 4 * h;
    float li = redf[wave][row];
    hob[(long)row * 512 + l31]      = bf16bits(accO0[r] * li);
    hob[(long)row * 512 + 32 + l31] = bf16bits(accO1[r] * li);
  }
}

// ---------------------------------------------------------------------------
// Launch
// ---------------------------------------------------------------------------
extern "C" void kernel_launch(void* const* d_in, const int* in_sizes, int n_in,
                              void* d_out, int out_size, void* d_ws, size_t ws_size,
                              hipStream_t stream) {
  const float* query = (const float*)d_in[0];
  const float* Wq = (const float*)d_in[1];
  const float* bq = (const float*)d_in[2];
  const float* Wk = (const float*)d_in[3];
  const float* bk = (const float*)d_in[4];
  const float* Wv = (const float*)d_in[5];
  const float* bv = (const float*)d_in[6];
  const float* Wo = (const float*)d_in[7];
  const float* bo = (const float*)d_in[8];

  char* ws = (char*)d_ws;
  u16* x_bf   = (u16*)(ws + 0);          // [8192][512]        8 MB
  u16* Wqk_t  = (u16*)(ws + 8388608);    // [1024][512]        1 MB
  u16* Wv_t   = (u16*)(ws + 9437184);    // [512][512]         0.5 MB
  u16* Wo_t   = (u16*)(ws + 9961472);    // [512][512]         0.5 MB
  u16* q_buf  = (u16*)(ws + 10485760);   // frag-ready Q       8 MB
  u16* k_buf  = (u16*)(ws + 18874368);   // frag-ready K       8 MB
  u16* v_buf  = (u16*)(ws + 27262976);   // frag-ready V       8 MB
  u16* ho_buf = (u16*)(ws + 35651584);   // [8192][512]        8 MB

  dim3 tb(32, 8, 1);
  transpose_f32_bf16<<<dim3(32, 16, 8), tb, 0, stream>>>(
      query, x_bf, 512, 1024, 512L * 1024, 1024L * 512, 512);
  wqkv_trans<<<dim3(2, 16, 24), tb, 0, stream>>>(Wq, Wk, Wv, Wqk_t, Wv_t);
  transpose_f32_bf16<<<dim3(16, 16, 1), tb, 0, stream>>>(
      Wo, Wo_t, 512, 512, 0L, 0L, 512);

  gemm_k<0><<<dim3(64, 8), 256, 0, stream>>>(x_bf, Wqk_t, bq, bk, q_buf, k_buf, nullptr);
  gemm_k<1><<<dim3(4, 64), 256, 0, stream>>>(Wv_t, x_bf, bv, nullptr, v_buf, nullptr, nullptr);

  attn_k<<<dim3(512), 256, 0, stream>>>(q_buf, k_buf, v_buf, ho_buf);

  gemm_k<2><<<dim3(4, 64), 256, 0, stream>>>(Wo_t, ho_buf, bo, nullptr, nullptr, nullptr, (float*)d_out);
}

// Round 13
// 162.710 us; speedup vs baseline: 1.3868x; 1.0031x over previous
//
#include <hip/hip_runtime.h>
#include <hip/hip_bf16.h>
#include <stdint.h>

// Problem constants
#define DIMC 512
#define NHEADS 8
#define HDIM 64
#define BATCH 8
#define NTOK 1024            // 32*32
#define MTOT (BATCH*NTOK)    // 8192

typedef __attribute__((ext_vector_type(8))) __bf16 bf16x8;
typedef __attribute__((ext_vector_type(4))) float f32x4;
typedef __attribute__((ext_vector_type(16))) float f32x16;
typedef __attribute__((ext_vector_type(4))) unsigned uint4v;
typedef unsigned short u16;

typedef const __attribute__((address_space(1))) uint8_t glob_u8;
typedef __attribute__((address_space(3))) uint8_t lds_u8;

#define LOG2E 1.44269504088896f
#define ATTN_SCALE 0.125f

__device__ __forceinline__ void gload16(const void* src, void* dst) {
  __builtin_amdgcn_global_load_lds((glob_u8*)src, (lds_u8*)dst, 16, 0, 0);
}

__device__ __forceinline__ u16 bf16bits(float v) {
  __hip_bfloat16 h = __float2bfloat16(v);
  return *(u16*)&h;
}

// v_cvt_pk_bf16_f32: pack two f32 -> two bf16 in one u32 (lo=first arg)
__device__ __forceinline__ unsigned cvtpk(float lo, float hi) {
  unsigned r;
  asm("v_cvt_pk_bf16_f32 %0, %1, %2" : "=v"(r) : "v"(lo), "v"(hi));
  return r;
}

// permlane32_swap pair: a' = [a.lo | b.lo(from lanes 0-31)], b' = [a.hi | b.hi]
__device__ __forceinline__ void plswap(unsigned &a, unsigned &b) {
  auto r = __builtin_amdgcn_permlane32_swap(a, b, false, false);
  a = r[0]; b = r[1];
}

__device__ __forceinline__ float xhalf_max(float x) {
  unsigned u = __builtin_bit_cast(unsigned, x);
  auto r = __builtin_amdgcn_permlane32_swap(u, u, false, false);
  return fmaxf(__builtin_bit_cast(float, r[0]), __builtin_bit_cast(float, r[1]));
}

__device__ __forceinline__ float xhalf_add(float x) {
  unsigned u = __builtin_bit_cast(unsigned, x);
  auto r = __builtin_amdgcn_permlane32_swap(u, u, false, false);
  return __builtin_bit_cast(float, r[0]) + __builtin_bit_cast(float, r[1]);
}

__device__ __forceinline__ bf16x8 mk8(unsigned a, unsigned b, unsigned c, unsigned d) {
  uint4v u; u.x = a; u.y = b; u.z = c; u.w = d;
  return __builtin_bit_cast(bf16x8, u);
}

// ---------------------------------------------------------------------------
// Transposes: f32 [R][C] -> bf16 [C][R-ish] tiles
// ---------------------------------------------------------------------------
__global__ void transpose_f32_bf16(const float* __restrict__ in,
                                   u16* __restrict__ out,
                                   int R, int C, long ibs, long obs, int ldo) {
  __shared__ float t[32][33];
  int bz = blockIdx.z;
  in  += (long)bz * ibs;
  out += (long)bz * obs;
  int r0 = blockIdx.y * 32, c0 = blockIdx.x * 32;
  int tx = threadIdx.x, ty = threadIdx.y;   // block (32, 8)
  #pragma unroll
  for (int i = 0; i < 4; ++i) {
    int r = r0 + ty + i * 8;
    t[ty + i * 8][tx] = in[(long)r * C + c0 + tx];
  }
  __syncthreads();
  #pragma unroll
  for (int i = 0; i < 4; ++i) {
    int c = c0 + ty + i * 8;
    out[(long)c * ldo + r0 + tx] = bf16bits(t[tx][ty + i * 8]);
  }
}

// Fused Wq/Wk/Wv transpose: grid (2, 16, 24); z = w*8+head
// Output: Wqkv_t rows [0,512)=Q^T, [512,1024)=K^T, [1024,1536)=V^T
__global__ void wqkv_trans(const float* __restrict__ Wq, const float* __restrict__ Wk,
                           const float* __restrict__ Wv, u16* __restrict__ Wqkv_t) {
  __shared__ float t[32][33];
  int z = blockIdx.z; int w = z >> 3, head = z & 7;
  const float* in = (w == 0 ? Wq : (w == 1 ? Wk : Wv)) + head * 32768;
  u16* out = Wqkv_t + w * 262144 + head * 32768;
  int r0 = blockIdx.y * 32, c0 = blockIdx.x * 32;
  int tx = threadIdx.x, ty = threadIdx.y;
  #pragma unroll
  for (int i = 0; i < 4; ++i) {
    int r = r0 + ty + i * 8;
    t[ty + i * 8][tx] = in[(long)r * 64 + c0 + tx];
  }
  __syncthreads();
  #pragma unroll
  for (int i = 0; i < 4; ++i) {
    int c = c0 + ty + i * 8;
    out[(long)c * 512 + r0 + tx] = bf16bits(t[tx][ty + i * 8]);
  }
}

// ---------------------------------------------------------------------------
// 128x128x(K=512) bf16 MFMA GEMM (m97-style, swizzled global_load_lds w16).
// MODE 0 (fused QKV): A = x [8192][512], Bt = Wqkv_t [1536][512]
//   cc>>9 selects {Q,K,V}; Q/K scatter to q_buf/k_buf frag layout
//     [bh][t32][ks4][lane64][j8]   (elem = X[bh][t*32+(l&31)][16ks+8(l>>5)+j])
//   V scatters to v_buf frag layout
//     [bh][kv32][ks2][n2][lane64][j8] (elem = V[bh][kv*32+16ks+8(l>>5)+j][32n+(l&31)])
// MODE 2: A = Wo_t [512][512], Bt = head_out [8192][512] -> f32 output
// ---------------------------------------------------------------------------
template<int MODE>
__global__ __launch_bounds__(256) void gemm_k(
    const u16* __restrict__ A, const u16* __restrict__ Bt,
    const float* __restrict__ bias0, const float* __restrict__ bias1,
    const float* __restrict__ bias2,
    u16* __restrict__ o0, u16* __restrict__ o1, u16* __restrict__ o2,
    float* __restrict__ of) {
  constexpr int K = 512;
  __shared__ __align__(16) char As[128 * 64 * 2];
  __shared__ __align__(16) char Bs[128 * 64 * 2];
  int tid = threadIdx.x, wave = tid >> 6, lane = tid & 63;
  int lo = lane & 15, hi = lane >> 4;
  int row0 = blockIdx.x * 128, col0 = blockIdx.y * 128;
  int wr = wave >> 1, wc = wave & 1;

  f32x4 acc[4][4] = {};

  const char* Ab = (const char*)A;
  const char* Bb = (const char*)Bt;

  for (int ks = 0; ks < 8; ++ks) {
    int k0 = ks * 64;
    #pragma unroll
    for (int i = 0; i < 4; ++i) {
      int ch = wave * 4 + i;
      int o = ch * 1024 + lane * 16;
      int r = o >> 7;                          // row within 128-row tile
      int w = (o & 127) ^ ((r & 7) << 4);      // swizzled within-row byte
      gload16(Ab + ((long)(row0 + r) * K + k0) * 2 + w, As + ch * 1024);
      gload16(Bb + ((long)(col0 + r) * K + k0) * 2 + w, Bs + ch * 1024);
    }
    __syncthreads();
    #pragma unroll
    for (int kk = 0; kk < 2; ++kk) {
      int kb = kk * 64 + hi * 16;
      bf16x8 af[4], bfr[4];
      #pragma unroll
      for (int m = 0; m < 4; ++m) {
        int r = wr * 64 + m * 16 + lo;
        af[m] = *(const bf16x8*)(As + ((r * 128 + kb) ^ ((r & 7) << 4)));
      }
      #pragma unroll
      for (int n = 0; n < 4; ++n) {
        int r = wc * 64 + n * 16 + lo;
        bfr[n] = *(const bf16x8*)(Bs + ((r * 128 + kb) ^ ((r & 7) << 4)));
      }
      #pragma unroll
      for (int m = 0; m < 4; ++m)
        #pragma unroll
        for (int n = 0; n < 4; ++n)
          acc[m][n] = __builtin_amdgcn_mfma_f32_16x16x32_bf16(af[m], bfr[n], acc[m][n], 0, 0, 0);
    }
    __syncthreads();
  }

  // epilogue: C/D frag layout  row = hi*4+r, col = lo
  #pragma unroll
  for (int m = 0; m < 4; ++m)
    #pragma unroll
    for (int n = 0; n < 4; ++n)
      #pragma unroll
      for (int r = 0; r < 4; ++r) {
        float v = acc[m][n][r];
        int rr = row0 + wr * 64 + m * 16 + hi * 4 + r;
        int cc = col0 + wc * 64 + n * 16 + lo;
        if constexpr (MODE == 0) {
          int b = rr >> 10, nn = rr & 1023;       // token
          int w = cc >> 9;                        // 0=Q 1=K 2=V
          int c2 = cc & 511;
          int head = c2 >> 6, d = c2 & 63;
          const float* bp = (w == 0) ? bias0 : (w == 1 ? bias1 : bias2);
          float val = v + bp[c2];
          int bh2 = b * 8 + head;
          u16 hb = bf16bits(val);
          if (w < 2) {
            // q_buf/k_buf: row-major tokens in frags
            int t = nn >> 5, l31q = nn & 31;
            int kss = d >> 4, hh = (d >> 3) & 1, j = d & 7;
            long off = (((long)(bh2 * 32 + t) * 4 + kss) * 64 + (l31q + 32 * hh)) * 8 + j;
            (w ? o1 : o0)[off] = hb;
          } else {
            // v_buf: key-major frags (B-operand of PV)
            int kv = nn >> 5, ki = nn & 31;
            int kss = ki >> 4, hh = (ki >> 3) & 1, j = ki & 7;
            int n2 = d >> 5, l31v = d & 31;
            long off = ((((long)(bh2 * 32 + kv) * 2 + kss) * 2 + n2) * 64 + (l31v + 32 * hh)) * 8 + j;
            o2[off] = hb;
          }
        } else {
          int b = cc >> 10, nn = cc & 1023;
          of[b * 524288 + rr * 1024 + nn] = v + bias0[rr];
        }
      }
}

// ---------------------------------------------------------------------------
// Flash attention, m214-style swapped-QK^T 32x32x16 structure.
// Grid: 512 blocks x 256 thr (4 independent waves; wave = 32 q-rows).
// No LDS tiles, no barriers. All operands read as frag-ready coalesced
// global loads (L2-resident). Softmax fully in-lane; P stays in registers
// via cvt_pk_bf16 + permlane32_swap; defer-max rescale (THR=8).
// ---------------------------------------------------------------------------
struct Frags { bf16x8 k[4]; bf16x8 v[2][2]; };

__device__ __forceinline__ void load_frags(Frags& f, const char* kb, const char* vb,
                                           int kv, int lane16) {
  const char* kp = kb + kv * 4096 + lane16;
  f.k[0] = *(const bf16x8*)(kp);
  f.k[1] = *(const bf16x8*)(kp + 1024);
  f.k[2] = *(const bf16x8*)(kp + 2048);
  f.k[3] = *(const bf16x8*)(kp + 3072);
  const char* vp = vb + kv * 4096 + lane16;
  f.v[0][0] = *(const bf16x8*)(vp);
  f.v[0][1] = *(const bf16x8*)(vp + 1024);
  f.v[1][0] = *(const bf16x8*)(vp + 2048);
  f.v[1][1] = *(const bf16x8*)(vp + 3072);
}

__global__ __launch_bounds__(256) void attn_k(
    const u16* __restrict__ qf, const u16* __restrict__ kf,
    const u16* __restrict__ vf, u16* __restrict__ ho) {
  __shared__ float redf[4][32];
  int tid = threadIdx.x, wave = tid >> 6, lane = tid & 63;
  int l31 = lane & 31, h = lane >> 5;
  // XCD-friendly decode: all 8 q-chunks of a bh on one XCD
  int id = blockIdx.x;                 // [0,512)
  int xcd = id & 7, rest = id >> 3;    // rest in [0,64)
  int bh = xcd * 8 + (rest >> 3);
  int qt = (rest & 7) * 4 + wave;      // 32-row q-tile [0,32)

  int lane16 = lane * 16;
  const char* qb = (const char*)qf + (long)(bh * 32 + qt) * 4096;
  const char* kb = (const char*)kf + (long)bh * 131072;
  const char* vb = (const char*)vf + (long)bh * 131072;

  bf16x8 qfrag[4];
  #pragma unroll
  for (int ks = 0; ks < 4; ++ks)
    qfrag[ks] = *(const bf16x8*)(qb + ks * 1024 + lane16);

  f32x16 accO0 = {}, accO1 = {};
  float mreg = -__builtin_inff(), lsum = 0.f;
  const float C1 = ATTN_SCALE * LOG2E;

  auto step = [&](const Frags& f) {
    f32x16 s = {};
    #pragma unroll
    for (int ks = 0; ks < 4; ++ks)
      s = __builtin_amdgcn_mfma_f32_32x32x16_bf16(f.k[ks], qfrag[ks], s, 0, 0, 0);
    // in-lane row max over 16 regs + cross-half swap
    float mx = fmaxf(s[0], s[1]);
    #pragma unroll
    for (int r = 2; r < 16; ++r) mx = fmaxf(mx, s[r]);
    mx = xhalf_max(mx);
    float scaled = mx * ATTN_SCALE;
    if (__any(scaled > mreg + 8.f)) {
      float mnew = fmaxf(mreg, scaled);
      float corr = exp2f((mreg - mnew) * LOG2E);
      redf[wave][l31] = corr;
      asm volatile("s_waitcnt lgkmcnt(0)" ::: "memory");
      #pragma unroll
      for (int r = 0; r < 16; ++r) {
        float cf = redf[wave][(r & 3) + 8 * (r >> 2) + 4 * h];
        accO0[r] *= cf; accO1[r] *= cf;
      }
      lsum *= corr;
      mreg = mnew;
    }
    float mb = mreg * LOG2E;
    float p[16]; float rs = 0.f;
    #pragma unroll
    for (int r = 0; r < 16; ++r) { p[r] = exp2f(fmaf(s[r], C1, -mb)); rs += p[r]; }
    lsum += xhalf_add(rs);
    // P (f32, P^T layout) -> bf16 A-frags via cvt_pk + permlane32_swap
    unsigned w0 = cvtpk(p[0], p[1]),  w1 = cvtpk(p[2], p[3]);
    unsigned w2 = cvtpk(p[4], p[5]),  w3 = cvtpk(p[6], p[7]);
    unsigned w4 = cvtpk(p[8], p[9]),  w5 = cvtpk(p[10], p[11]);
    unsigned w6 = cvtpk(p[12], p[13]), w7 = cvtpk(p[14], p[15]);
    plswap(w0, w2); plswap(w1, w3); plswap(w4, w6); plswap(w5, w7);
    bf16x8 pa0 = mk8(w0, w1, w2, w3);
    bf16x8 pa1 = mk8(w4, w5, w6, w7);
    accO0 = __builtin_amdgcn_mfma_f32_32x32x16_bf16(pa0, f.v[0][0], accO0, 0, 0, 0);
    accO0 = __builtin_amdgcn_mfma_f32_32x32x16_bf16(pa1, f.v[1][0], accO0, 0, 0, 0);
    accO1 = __builtin_amdgcn_mfma_f32_32x32x16_bf16(pa0, f.v[0][1], accO1, 0, 0, 0);
    accO1 = __builtin_amdgcn_mfma_f32_32x32x16_bf16(pa1, f.v[1][1], accO1, 0, 0, 0);
  };

  Frags fA, fB;
  load_frags(fA, kb, vb, 0, lane16);
  for (int i = 0; i < 16; ++i) {
    load_frags(fB, kb, vb, 2 * i + 1, lane16);
    step(fA);
    if (i < 15) load_frags(fA, kb, vb, 2 * i + 2, lane16);
    step(fB);
  }

  // epilogue: redistribute 1/lsum across the C-layout rows, write head_out
  float linv = 1.f / lsum;
  redf[wave][l31] = linv;
  asm volatile("s_waitcnt lgkmcnt(0)" ::: "memory");
  int b = bh >> 3, head = bh & 7;
  u16* hob = ho + ((long)b * 1024 + qt * 32) * 512 + head * 64;
  #pragma unroll
  for (int r = 0; r < 16; ++r) {
    int row = (r & 3) + 8 * (r >> 2) + 4 * h;
    float li = redf[wave][row];
    hob[(long)row * 512 + l31]      = bf16bits(accO0[r] * li);
    hob[(long)row * 512 + 32 + l31] = bf16bits(accO1[r] * li);
  }
}

// ---------------------------------------------------------------------------
// Launch
// ---------------------------------------------------------------------------
extern "C" void kernel_launch(void* const* d_in, const int* in_sizes, int n_in,
                              void* d_out, int out_size, void* d_ws, size_t ws_size,
                              hipStream_t stream) {
  const float* query = (const float*)d_in[0];
  const float* Wq = (const float*)d_in[1];
  const float* bq = (const float*)d_in[2];
  const float* Wk = (const float*)d_in[3];
  const float* bk = (const float*)d_in[4];
  const float* Wv = (const float*)d_in[5];
  const float* bv = (const float*)d_in[6];
  const float* Wo = (const float*)d_in[7];
  const float* bo = (const float*)d_in[8];

  char* ws = (char*)d_ws;
  u16* x_bf    = (u16*)(ws + 0);          // [8192][512]        8 MB
  u16* Wqkv_t  = (u16*)(ws + 8388608);    // [1536][512]        1.5 MB
  u16* Wo_t    = (u16*)(ws + 9961472);    // [512][512]         0.5 MB
  u16* q_buf   = (u16*)(ws + 10485760);   // frag-ready Q       8 MB
  u16* k_buf   = (u16*)(ws + 18874368);   // frag-ready K       8 MB
  u16* v_buf   = (u16*)(ws + 27262976);   // frag-ready V       8 MB
  u16* ho_buf  = (u16*)(ws + 35651584);   // [8192][512]        8 MB

  dim3 tb(32, 8, 1);
  transpose_f32_bf16<<<dim3(32, 16, 8), tb, 0, stream>>>(
      query, x_bf, 512, 1024, 512L * 1024, 1024L * 512, 512);
  wqkv_trans<<<dim3(2, 16, 24), tb, 0, stream>>>(Wq, Wk, Wv, Wqkv_t);
  transpose_f32_bf16<<<dim3(16, 16, 1), tb, 0, stream>>>(
      Wo, Wo_t, 512, 512, 0L, 0L, 512);

  // Fused QKV projection: N = 1536 (Q|K|V)
  gemm_k<0><<<dim3(64, 12), 256, 0, stream>>>(
      x_bf, Wqkv_t, bq, bk, bv, q_buf, k_buf, v_buf, nullptr);

  attn_k<<<dim3(512), 256, 0, stream>>>(q_buf, k_buf, v_buf, ho_buf);

  gemm_k<2><<<dim3(4, 64), 256, 0, stream>>>(
      Wo_t, ho_buf, bo, nullptr, nullptr, nullptr, nullptr, nullptr, (float*)d_out);
}

// Round 17
// 158.148 us; speedup vs baseline: 1.4268x; 1.0288x over previous
//
#include <hip/hip_runtime.h>
#include <hip/hip_bf16.h>
#include <stdint.h>

// Problem constants
#define DIMC 512
#define NHEADS 8
#define HDIM 64
#define BATCH 8
#define NTOK 1024            // 32*32
#define MTOT (BATCH*NTOK)    // 8192

typedef __attribute__((ext_vector_type(8))) __bf16 bf16x8;
typedef __attribute__((ext_vector_type(4))) float f32x4;
typedef __attribute__((ext_vector_type(16))) float f32x16;
typedef __attribute__((ext_vector_type(4))) unsigned uint4v;
typedef unsigned short u16;

typedef const __attribute__((address_space(1))) uint8_t glob_u8;
typedef __attribute__((address_space(3))) uint8_t lds_u8;

#define LOG2E 1.44269504088896f
#define ATTN_SCALE 0.125f

__device__ __forceinline__ void gload16(const void* src, void* dst) {
  __builtin_amdgcn_global_load_lds((glob_u8*)src, (lds_u8*)dst, 16, 0, 0);
}

__device__ __forceinline__ u16 bf16bits(float v) {
  __hip_bfloat16 h = __float2bfloat16(v);
  return *(u16*)&h;
}

// v_cvt_pk_bf16_f32: pack two f32 -> two bf16 in one u32 (lo=first arg)
__device__ __forceinline__ unsigned cvtpk(float lo, float hi) {
  unsigned r;
  asm("v_cvt_pk_bf16_f32 %0, %1, %2" : "=v"(r) : "v"(lo), "v"(hi));
  return r;
}

// permlane32_swap pair: a' = [a.lo | b.lo(from lanes 0-31)], b' = [a.hi | b.hi]
__device__ __forceinline__ void plswap(unsigned &a, unsigned &b) {
  auto r = __builtin_amdgcn_permlane32_swap(a, b, false, false);
  a = r[0]; b = r[1];
}

__device__ __forceinline__ float xhalf_max(float x) {
  unsigned u = __builtin_bit_cast(unsigned, x);
  auto r = __builtin_amdgcn_permlane32_swap(u, u, false, false);
  return fmaxf(__builtin_bit_cast(float, r[0]), __builtin_bit_cast(float, r[1]));
}

__device__ __forceinline__ float xhalf_add(float x) {
  unsigned u = __builtin_bit_cast(unsigned, x);
  auto r = __builtin_amdgcn_permlane32_swap(u, u, false, false);
  return __builtin_bit_cast(float, r[0]) + __builtin_bit_cast(float, r[1]);
}

__device__ __forceinline__ bf16x8 mk8(unsigned a, unsigned b, unsigned c, unsigned d) {
  uint4v u; u.x = a; u.y = b; u.z = c; u.w = d;
  return __builtin_bit_cast(bf16x8, u);
}

// ---------------------------------------------------------------------------
// Transposes: f32 [R][C] -> bf16 [C][R-ish] tiles
// ---------------------------------------------------------------------------
__global__ void transpose_f32_bf16(const float* __restrict__ in,
                                   u16* __restrict__ out,
                                   int R, int C, long ibs, long obs, int ldo) {
  __shared__ float t[32][33];
  int bz = blockIdx.z;
  in  += (long)bz * ibs;
  out += (long)bz * obs;
  int r0 = blockIdx.y * 32, c0 = blockIdx.x * 32;
  int tx = threadIdx.x, ty = threadIdx.y;   // block (32, 8)
  #pragma unroll
  for (int i = 0; i < 4; ++i) {
    int r = r0 + ty + i * 8;
    t[ty + i * 8][tx] = in[(long)r * C + c0 + tx];
  }
  __syncthreads();
  #pragma unroll
  for (int i = 0; i < 4; ++i) {
    int c = c0 + ty + i * 8;
    out[(long)c * ldo + r0 + tx] = bf16bits(t[tx][ty + i * 8]);
  }
}

// Fused Wq/Wk/Wv transpose: grid (2, 16, 24); z = w*8+head
// Output: Wqkv_t rows [0,512)=Q^T, [512,1024)=K^T, [1024,1536)=V^T
__global__ void wqkv_trans(const float* __restrict__ Wq, const float* __restrict__ Wk,
                           const float* __restrict__ Wv, u16* __restrict__ Wqkv_t) {
  __shared__ float t[32][33];
  int z = blockIdx.z; int w = z >> 3, head = z & 7;
  const float* in = (w == 0 ? Wq : (w == 1 ? Wk : Wv)) + head * 32768;
  u16* out = Wqkv_t + w * 262144 + head * 32768;
  int r0 = blockIdx.y * 32, c0 = blockIdx.x * 32;
  int tx = threadIdx.x, ty = threadIdx.y;
  #pragma unroll
  for (int i = 0; i < 4; ++i) {
    int r = r0 + ty + i * 8;
    t[ty + i * 8][tx] = in[(long)r * 64 + c0 + tx];
  }
  __syncthreads();
  #pragma unroll
  for (int i = 0; i < 4; ++i) {
    int c = c0 + ty + i * 8;
    out[(long)c * 512 + r0 + tx] = bf16bits(t[tx][ty + i * 8]);
  }
}

// ---------------------------------------------------------------------------
// 128x128x(K=512) bf16 MFMA GEMM, 8 waves/block (512 thr) for latency hiding.
// Wave grid 2x4: wave wr=wave>>2 (64 rows), wc=wave&3 (32 cols); acc[4][2].
// Staging: swizzled global_load_lds w16 (2 chunks/wave per matrix per K-step).
// MODE 0 (fused QKV): A = x [8192][512], Bt = Wqkv_t [1536][512]
//   cc>>9 selects {Q,K,V}; Q/K scatter to q_buf/k_buf frag layout
//     [bh][t32][ks4][lane64][j8]   (elem = X[bh][t*32+(l&31)][16ks+8(l>>5)+j])
//   V scatters to v_buf frag layout
//     [bh][kv32][ks2][n2][lane64][j8] (elem = V[bh][kv*32+16ks+8(l>>5)+j][32n+(l&31)])
// MODE 2: A = Wo_t [512][512], Bt = head_out [8192][512] -> f32 output
// ---------------------------------------------------------------------------
template<int MODE>
__global__ __launch_bounds__(512) void gemm_k(
    const u16* __restrict__ A, const u16* __restrict__ Bt,
    const float* __restrict__ bias0, const float* __restrict__ bias1,
    const float* __restrict__ bias2,
    u16* __restrict__ o0, u16* __restrict__ o1, u16* __restrict__ o2,
    float* __restrict__ of) {
  constexpr int K = 512;
  __shared__ __align__(16) char As[128 * 64 * 2];
  __shared__ __align__(16) char Bs[128 * 64 * 2];
  int tid = threadIdx.x, wave = tid >> 6, lane = tid & 63;
  int lo = lane & 15, hi = lane >> 4;
  int row0 = blockIdx.x * 128, col0 = blockIdx.y * 128;
  int wr = wave >> 2, wc = wave & 3;     // 2x4 wave grid; wave owns 64x32

  f32x4 acc[4][2] = {};

  const char* Ab = (const char*)A;
  const char* Bb = (const char*)Bt;

  for (int ks = 0; ks < 8; ++ks) {
    int k0 = ks * 64;
    #pragma unroll
    for (int i = 0; i < 2; ++i) {
      int ch = wave * 2 + i;                   // 16 chunks cover 16KB tile
      int o = ch * 1024 + lane * 16;
      int r = o >> 7;                          // row within 128-row tile
      int w = (o & 127) ^ ((r & 7) << 4);      // swizzled within-row byte
      gload16(Ab + ((long)(row0 + r) * K + k0) * 2 + w, As + ch * 1024);
      gload16(Bb + ((long)(col0 + r) * K + k0) * 2 + w, Bs + ch * 1024);
    }
    __syncthreads();
    #pragma unroll
    for (int kk = 0; kk < 2; ++kk) {
      int kb = kk * 64 + hi * 16;
      bf16x8 af[4], bfr[2];
      #pragma unroll
      for (int m = 0; m < 4; ++m) {
        int r = wr * 64 + m * 16 + lo;
        af[m] = *(const bf16x8*)(As + ((r * 128 + kb) ^ ((r & 7) << 4)));
      }
      #pragma unroll
      for (int n = 0; n < 2; ++n) {
        int r = wc * 32 + n * 16 + lo;
        bfr[n] = *(const bf16x8*)(Bs + ((r * 128 + kb) ^ ((r & 7) << 4)));
      }
      #pragma unroll
      for (int m = 0; m < 4; ++m)
        #pragma unroll
        for (int n = 0; n < 2; ++n)
          acc[m][n] = __builtin_amdgcn_mfma_f32_16x16x32_bf16(af[m], bfr[n], acc[m][n], 0, 0, 0);
    }
    __syncthreads();
  }

  // epilogue: C/D frag layout  row = hi*4+r, col = lo
  #pragma unroll
  for (int m = 0; m < 4; ++m)
    #pragma unroll
    for (int n = 0; n < 2; ++n)
      #pragma unroll
      for (int r = 0; r < 4; ++r) {
        float v = acc[m][n][r];
        int rr = row0 + wr * 64 + m * 16 + hi * 4 + r;
        int cc = col0 + wc * 32 + n * 16 + lo;
        if constexpr (MODE == 0) {
          int b = rr >> 10, nn = rr & 1023;       // token
          int w = cc >> 9;                        // 0=Q 1=K 2=V
          int c2 = cc & 511;
          int head = c2 >> 6, d = c2 & 63;
          const float* bp = (w == 0) ? bias0 : (w == 1 ? bias1 : bias2);
          float val = v + bp[c2];
          int bh2 = b * 8 + head;
          u16 hb = bf16bits(val);
          if (w < 2) {
            // q_buf/k_buf: row-major tokens in frags
            int t = nn >> 5, l31q = nn & 31;
            int kss = d >> 4, hh = (d >> 3) & 1, j = d & 7;
            long off = (((long)(bh2 * 32 + t) * 4 + kss) * 64 + (l31q + 32 * hh)) * 8 + j;
            (w ? o1 : o0)[off] = hb;
          } else {
            // v_buf: key-major frags (B-operand of PV)
            int kv = nn >> 5, ki = nn & 31;
            int kss = ki >> 4, hh = (ki >> 3) & 1, j = ki & 7;
            int n2 = d >> 5, l31v = d & 31;
            long off = ((((long)(bh2 * 32 + kv) * 2 + kss) * 2 + n2) * 64 + (l31v + 32 * hh)) * 8 + j;
            o2[off] = hb;
          }
        } else {
          int b = cc >> 10, nn = cc & 1023;
          of[b * 524288 + rr * 1024 + nn] = v + bias0[rr];
        }
      }
}

// ---------------------------------------------------------------------------
// Flash attention, m214-style swapped-QK^T 32x32x16 structure.
// Grid: 512 blocks x 256 thr (4 independent waves; wave = 32 q-rows).
// No LDS tiles, no barriers. All operands read as frag-ready coalesced
// global loads (L2-resident). Softmax fully in-lane; P stays in registers
// via cvt_pk_bf16 + permlane32_swap; defer-max rescale (THR=8).
// ---------------------------------------------------------------------------
struct Frags { bf16x8 k[4]; bf16x8 v[2][2]; };

__device__ __forceinline__ void load_frags(Frags& f, const char* kb, const char* vb,
                                           int kv, int lane16) {
  const char* kp = kb + kv * 4096 + lane16;
  f.k[0] = *(const bf16x8*)(kp);
  f.k[1] = *(const bf16x8*)(kp + 1024);
  f.k[2] = *(const bf16x8*)(kp + 2048);
  f.k[3] = *(const bf16x8*)(kp + 3072);
  const char* vp = vb + kv * 4096 + lane16;
  f.v[0][0] = *(const bf16x8*)(vp);
  f.v[0][1] = *(const bf16x8*)(vp + 1024);
  f.v[1][0] = *(const bf16x8*)(vp + 2048);
  f.v[1][1] = *(const bf16x8*)(vp + 3072);
}

__global__ __launch_bounds__(256) void attn_k(
    const u16* __restrict__ qf, const u16* __restrict__ kf,
    const u16* __restrict__ vf, u16* __restrict__ ho) {
  __shared__ float redf[4][32];
  int tid = threadIdx.x, wave = tid >> 6, lane = tid & 63;
  int l31 = lane & 31, h = lane >> 5;
  // XCD-friendly decode: all 8 q-chunks of a bh on one XCD
  int id = blockIdx.x;                 // [0,512)
  int xcd = id & 7, rest = id >> 3;    // rest in [0,64)
  int bh = xcd * 8 + (rest >> 3);
  int qt = (rest & 7) * 4 + wave;      // 32-row q-tile [0,32)

  int lane16 = lane * 16;
  const char* qb = (const char*)qf + (long)(bh * 32 + qt) * 4096;
  const char* kb = (const char*)kf + (long)bh * 131072;
  const char* vb = (const char*)vf + (long)bh * 131072;

  bf16x8 qfrag[4];
  #pragma unroll
  for (int ks = 0; ks < 4; ++ks)
    qfrag[ks] = *(const bf16x8*)(qb + ks * 1024 + lane16);

  f32x16 accO0 = {}, accO1 = {};
  float mreg = -__builtin_inff(), lsum = 0.f;
  const float C1 = ATTN_SCALE * LOG2E;

  auto step = [&](const Frags& f) {
    f32x16 s = {};
    #pragma unroll
    for (int ks = 0; ks < 4; ++ks)
      s = __builtin_amdgcn_mfma_f32_32x32x16_bf16(f.k[ks], qfrag[ks], s, 0, 0, 0);
    // in-lane row max over 16 regs + cross-half swap
    float mx = fmaxf(s[0], s[1]);
    #pragma unroll
    for (int r = 2; r < 16; ++r) mx = fmaxf(mx, s[r]);
    mx = xhalf_max(mx);
    float scaled = mx * ATTN_SCALE;
    if (__any(scaled > mreg + 8.f)) {
      float mnew = fmaxf(mreg, scaled);
      float corr = exp2f((mreg - mnew) * LOG2E);
      redf[wave][l31] = corr;
      asm volatile("s_waitcnt lgkmcnt(0)" ::: "memory");
      #pragma unroll
      for (int r = 0; r < 16; ++r) {
        float cf = redf[wave][(r & 3) + 8 * (r >> 2) + 4 * h];
        accO0[r] *= cf; accO1[r] *= cf;
      }
      lsum *= corr;
      mreg = mnew;
    }
    float mb = mreg * LOG2E;
    float p[16]; float rs = 0.f;
    #pragma unroll
    for (int r = 0; r < 16; ++r) { p[r] = exp2f(fmaf(s[r], C1, -mb)); rs += p[r]; }
    lsum += xhalf_add(rs);
    // P (f32, P^T layout) -> bf16 A-frags via cvt_pk + permlane32_swap
    unsigned w0 = cvtpk(p[0], p[1]),  w1 = cvtpk(p[2], p[3]);
    unsigned w2 = cvtpk(p[4], p[5]),  w3 = cvtpk(p[6], p[7]);
    unsigned w4 = cvtpk(p[8], p[9]),  w5 = cvtpk(p[10], p[11]);
    unsigned w6 = cvtpk(p[12], p[13]), w7 = cvtpk(p[14], p[15]);
    plswap(w0, w2); plswap(w1, w3); plswap(w4, w6); plswap(w5, w7);
    bf16x8 pa0 = mk8(w0, w1, w2, w3);
    bf16x8 pa1 = mk8(w4, w5, w6, w7);
    accO0 = __builtin_amdgcn_mfma_f32_32x32x16_bf16(pa0, f.v[0][0], accO0, 0, 0, 0);
    accO0 = __builtin_amdgcn_mfma_f32_32x32x16_bf16(pa1, f.v[1][0], accO0, 0, 0, 0);
    accO1 = __builtin_amdgcn_mfma_f32_32x32x16_bf16(pa0, f.v[0][1], accO1, 0, 0, 0);
    accO1 = __builtin_amdgcn_mfma_f32_32x32x16_bf16(pa1, f.v[1][1], accO1, 0, 0, 0);
  };

  Frags fA, fB;
  load_frags(fA, kb, vb, 0, lane16);
  for (int i = 0; i < 16; ++i) {
    load_frags(fB, kb, vb, 2 * i + 1, lane16);
    step(fA);
    if (i < 15) load_frags(fA, kb, vb, 2 * i + 2, lane16);
    step(fB);
  }

  // epilogue: redistribute 1/lsum across the C-layout rows, write head_out
  float linv = 1.f / lsum;
  redf[wave][l31] = linv;
  asm volatile("s_waitcnt lgkmcnt(0)" ::: "memory");
  int b = bh >> 3, head = bh & 7;
  u16* hob = ho + ((long)b * 1024 + qt * 32) * 512 + head * 64;
  #pragma unroll
  for (int r = 0; r < 16; ++r) {
    int row = (r & 3) + 8 * (r >> 2) + 4 * h;
    float li = redf[wave][row];
    hob[(long)row * 512 + l31]      = bf16bits(accO0[r] * li);
    hob[(long)row * 512 + 32 + l31] = bf16bits(accO1[r] * li);
  }
}

// ---------------------------------------------------------------------------
// Launch
// ---------------------------------------------------------------------------
extern "C" void kernel_launch(void* const* d_in, const int* in_sizes, int n_in,
                              void* d_out, int out_size, void* d_ws, size_t ws_size,
                              hipStream_t stream) {
  const float* query = (const float*)d_in[0];
  const float* Wq = (const float*)d_in[1];
  const float* bq = (const float*)d_in[2];
  const float* Wk = (const float*)d_in[3];
  const float* bk = (const float*)d_in[4];
  const float* Wv = (const float*)d_in[5];
  const float* bv = (const float*)d_in[6];
  const float* Wo = (const float*)d_in[7];
  const float* bo = (const float*)d_in[8];

  char* ws = (char*)d_ws;
  u16* x_bf    = (u16*)(ws + 0);          // [8192][512]        8 MB
  u16* Wqkv_t  = (u16*)(ws + 8388608);    // [1536][512]        1.5 MB
  u16* Wo_t    = (u16*)(ws + 9961472);    // [512][512]         0.5 MB
  u16* q_buf   = (u16*)(ws + 10485760);   // frag-ready Q       8 MB
  u16* k_buf   = (u16*)(ws + 18874368);   // frag-ready K       8 MB
  u16* v_buf   = (u16*)(ws + 27262976);   // frag-ready V       8 MB
  u16* ho_buf  = (u16*)(ws + 35651584);   // [8192][512]        8 MB

  dim3 tb(32, 8, 1);
  transpose_f32_bf16<<<dim3(32, 16, 8), tb, 0, stream>>>(
      query, x_bf, 512, 1024, 512L * 1024, 1024L * 512, 512);
  wqkv_trans<<<dim3(2, 16, 24), tb, 0, stream>>>(Wq, Wk, Wv, Wqkv_t);
  transpose_f32_bf16<<<dim3(16, 16, 1), tb, 0, stream>>>(
      Wo, Wo_t, 512, 512, 0L, 0L, 512);

  // Fused QKV projection: N = 1536 (Q|K|V), 512-thread blocks
  gemm_k<0><<<dim3(64, 12), 512, 0, stream>>>(
      x_bf, Wqkv_t, bq, bk, bv, q_buf, k_buf, v_buf, nullptr);

  attn_k<<<dim3(512), 256, 0, stream>>>(q_buf, k_buf, v_buf, ho_buf);

  gemm_k<2><<<dim3(4, 64), 512, 0, stream>>>(
      Wo_t, ho_buf, bo, nullptr, nullptr, nullptr, nullptr, nullptr, (float*)d_out);
}